// Round 14
// baseline (202.935 us; speedup 1.0000x reference)
//
#include <hip/hip_runtime.h>
#include <math.h>

#define PI_F      3.141592653f
#define TWO_PI_F  6.283185306f
#define HALF_PI_F 1.5707963265f
#define IOU_THR_F 0.1f

typedef unsigned long long u64;

__device__ __forceinline__ float limit_period_f(float v) {
    return v - floorf(v / TWO_PI_F + 0.5f) * TWO_PI_F;
}

__device__ __forceinline__ u64 shfl_u64(u64 v, int src) {
    unsigned int lo = (unsigned int)(v & 0xffffffffull);
    unsigned int hi = (unsigned int)(v >> 32);
    lo = __shfl((int)lo, src);
    hi = __shfl((int)hi, src);
    return ((u64)hi << 32) | (u64)lo;
}

// ---------------- Kernel 1: adjacency + occByte (single-producer, no atomics) -
// Thread owns (row i, word w): 64 in-register IoUs vs LDS-staged j-boxes.
// adjC[(size_t)w * n + i] = word w of row i.
// occByte[rb*64 + w] = 1 iff any row in block rb has nonzero word w.
__global__ void adj_kernel(const float* __restrict__ boxes,
                           u64* __restrict__ adjC,
                           unsigned char* __restrict__ occByte,
                           int n, int words) {
    __shared__ float jS[7][64];
    int w = blockIdx.x;
    int tid = threadIdx.x;              // 256 = 4 waves
    int lane = tid & 63, wv = tid >> 6;
    if (tid < 64) {
        int j = (w << 6) + tid;
        if (j < n) {
            float b0 = boxes[j*7+0], b1 = boxes[j*7+1], b2 = boxes[j*7+2];
            float b3 = boxes[j*7+3], b4 = boxes[j*7+4], b5 = boxes[j*7+5];
            jS[0][tid] = b0 - b5*0.5f;  jS[3][tid] = b0 + b5*0.5f;
            jS[1][tid] = b1 - b4*0.5f;  jS[4][tid] = b1 + b4*0.5f;
            jS[2][tid] = b2 - b3*0.5f;  jS[5][tid] = b2 + b3*0.5f;
            jS[6][tid] = (b5*b4)*b3;
        }
    }
    __syncthreads();
    int i = blockIdx.y * 256 + tid;
    u64 word = 0ull;
    if (i < n) {
        float b0 = boxes[i*7+0], b1 = boxes[i*7+1], b2 = boxes[i*7+2];
        float b3 = boxes[i*7+3], b4 = boxes[i*7+4], b5 = boxes[i*7+5];
        float lix = b0 - b5*0.5f, hix = b0 + b5*0.5f;
        float liy = b1 - b4*0.5f, hiy = b1 + b4*0.5f;
        float liz = b2 - b3*0.5f, hiz = b2 + b3*0.5f;
        float vi  = (b5*b4)*b3;
        int jmax = n - (w << 6); if (jmax > 64) jmax = 64;
        for (int jj = 0; jj < jmax; ++jj) {
            float ix = fminf(hix, jS[3][jj]) - fmaxf(lix, jS[0][jj]); ix = fmaxf(ix, 0.0f);
            float iy = fminf(hiy, jS[4][jj]) - fmaxf(liy, jS[1][jj]); iy = fmaxf(iy, 0.0f);
            float iz = fminf(hiz, jS[5][jj]) - fmaxf(liz, jS[2][jj]); iz = fmaxf(iz, 0.0f);
            float inter = (ix*iy)*iz;
            float u = fmaxf(vi + jS[6][jj] - inter, 1e-8f);
            bool pred = (inter / u) > IOU_THR_F;
            word |= ((u64)(pred ? 1 : 0)) << jj;
        }
        adjC[(size_t)w * n + i] = word;
    }
    u64 bal = __ballot((i < n) && word != 0ull);
    int rb = blockIdx.y * 4 + wv;
    if (lane == 0 && rb < 64)
        occByte[rb * 64 + w] = bal ? (unsigned char)1 : (unsigned char)0;
}

// ---------------- Kernel 2: component-parallel exact greedy MIS ---------------
// Word-graph: words e,w adjacent iff tile (e,w) occupied. The ordered greedy is
// exact per word-component. Each block: build occ graph (coalesced ballots),
// min-label propagation in registers, then the block whose index is a
// component leader runs the ordered chain over its few member words.
// Zero inter-block coordination; every word written by exactly one block.
__global__ __launch_bounds__(64) void miscomp_kernel(
        const u64* __restrict__ adjC,
        const unsigned char* __restrict__ occByte,
        u64* __restrict__ S,
        int n, int words) {
    int lane = threadIdx.x;        // 64 = 1 wave
    int wB = blockIdx.x;
    if (wB >= words) return;
    // colMask[lane] = word-graph adjacency of word `lane` (symmetric occ)
    u64 colMask = 0ull;
    for (int rb = 0; rb < 64; ++rb) {
        unsigned char b = occByte[rb * 64 + lane];     // coalesced across lanes
        colMask |= ((u64)(b ? 1 : 0)) << rb;
    }
    // min-label propagation (convergence-checked; diag always occupied)
    int label = lane;
    for (int it = 0; it < 64; ++it) {
        int old = label;
        u64 m = colMask;
        while (m) {
            int b = (int)__ffsll(m) - 1; m &= m - 1;
            int nl = __shfl(label, b);
            label = min(label, nl);
        }
        u64 ch = __ballot(label != old);
        if (ch == 0ull) break;
    }
    int leader = __shfl(label, wB);
    if (leader != wB) return;      // this block is not a component leader
    u64 members = __ballot(label == wB);
    // ordered exact greedy over member words ascending; lane e holds S[e]
    u64 S_reg = 0ull;
    u64 mm = members;
    while (mm) {
        int w2 = (int)__ffsll(mm) - 1; mm &= mm - 1;
        int base2 = w2 << 6;
        int i2 = base2 + lane;
        int vb = n - base2;
        u64 valid = (vb >= 64) ? ~0ull : ((vb <= 0) ? 0ull : ((1ull << vb) - 1ull));
        u64 Adiag = (i2 < n) ? adjC[(size_t)w2 * n + i2] : 0ull;
        // em: node has a seed neighbor in an earlier member word
        bool anySeed = false;
        u64 ew = shfl_u64(colMask, w2) & members & (w2 ? ((1ull << w2) - 1ull) : 0ull);
        while (ew) {
            int e = (int)__ffsll(ew) - 1; ew &= ew - 1;
            u64 Se = shfl_u64(S_reg, e);               // uniform
            if (Se) {
                u64 row = (i2 < n) ? adjC[(size_t)e * n + i2] : 0ull;
                if (row & Se) anySeed = true;
            }
        }
        u64 em = __ballot(anySeed);
        u64 cand = valid & ~em;
        u64 s = 0ull;
        while (cand) {                 // exact in-word ascending greedy
            int b = (int)__ffsll(cand) - 1;
            s |= 1ull << b;
            u64 Ab = shfl_u64(Adiag, b);
            cand &= ~Ab;
            u64 him = (b >= 63) ? 0ull : ~((2ull << b) - 1ull);
            cand &= him;
        }
        if (lane == w2) S_reg = s;     // s is wave-uniform
    }
    if ((members >> lane) & 1ull) S[lane] = S_reg;
}

// ---------------- Kernel 3: indices + seedList + nclust (occ-guided) ----------
// indices[j] = rank of max-index adjacent seed (last-writer-wins semantics).
__global__ void indices_kernel(const u64* __restrict__ adjC,
                               const unsigned char* __restrict__ occByte,
                               const u64* __restrict__ S,
                               int* __restrict__ indices,
                               int* __restrict__ seedList,
                               int* __restrict__ nclust, int n, int words) {
    __shared__ u64 smS[64];
    __shared__ int wsS[64];
    int tid = threadIdx.x;  // 256
    int lane = tid & 63, wv = tid >> 6;
    if (tid < 64) {
        u64 s = (tid < words) ? S[tid] : 0ull;
        smS[tid] = s;
        int pc = (int)__popcll(s);
        int x = pc;
        for (int o = 1; o < 64; o <<= 1) {
            int y = __shfl_up(x, o);
            if (tid >= o) x += y;
        }
        wsS[tid] = x - pc;              // exclusive scan
        if (blockIdx.x == 0 && tid == 63) *nclust = x;
    }
    __syncthreads();
    int rb = blockIdx.x * 4 + wv;       // wave-uniform row-block
    unsigned char ob = (rb < 64) ? occByte[rb * 64 + lane] : 0;
    u64 occR = __ballot(ob != 0);
    int j = blockIdx.x * 256 + tid;
    if (j >= n) return;
    int best = -1;
    u64 tmp = occR;
    while (tmp) {
        int w2 = (int)__ffsll(tmp) - 1; tmp &= tmp - 1;
        u64 m = adjC[(size_t)w2 * n + j] & smS[w2];   // coalesced across j
        if (m) best = (w2 << 6) + 63 - (int)__clzll(m);
    }
    int idx = 0;
    if (best >= 0) {
        int w2 = best >> 6, b = best & 63;
        u64 incl = (b >= 63) ? ~0ull : ((2ull << b) - 1ull);
        idx = wsS[w2] + (int)__popcll(smS[w2] & incl);  // 1-based cid
    }
    indices[j] = idx;
    int wj = j >> 6, bj = j & 63;
    if ((smS[wj] >> bj) & 1ull) {
        int rank = wsS[wj] + (int)__popcll(smS[wj] & (bj ? ((1ull << bj) - 1ull) : 0ull)) + 1;
        seedList[rank - 1] = j;
    }
}

// ---------------- Kernel 4: per-cluster fusion (grid-stride, 1 wave/block) ----
__global__ void fusion_kernel(const float* __restrict__ boxes,
                              const float* __restrict__ scores,
                              const int* __restrict__ indices,
                              const int* __restrict__ seedListG,
                              const int* __restrict__ nclust,
                              const u64* __restrict__ adjC,
                              float* __restrict__ fused,
                              float* __restrict__ sfused,
                              int* __restrict__ validArr, int n, int words) {
    int lane = threadIdx.x;       // 64 = 1 wave
    int nc = *nclust;
    __shared__ unsigned short js[256];
    __shared__ float ms[256];
    __shared__ float ds[256];
    for (int i = blockIdx.x; i < n; i += gridDim.x) {
        int cid = i + 1;
        if (cid > nc) {
            if (lane < 7) fused[i*7+lane] = 0.0f;
            if (lane == 0) { sfused[i] = 0.0f; validArr[i] = 0; }
            continue;
        }
        int s = seedListG[i];
        u64 bits = (lane < words) ? adjC[(size_t)lane * n + s] : 0ull;
        // filter: keep only nodes whose final cluster is cid
        u64 keep = 0ull;
        u64 t = bits;
        while (t) {
            int b = (int)__ffsll(t) - 1;
            t &= t - 1;
            int node = (lane << 6) + b;
            if (indices[node] == cid) keep |= (1ull << b);
        }
        int cnt = __popcll(keep);
        int x = cnt;
        for (int o = 1; o < 64; o <<= 1) {
            int y = __shfl_up(x, o);
            if (lane >= o) x += y;
        }
        int excl = x - cnt;
        int m = __shfl(x, 63);
        int pos = excl;
        t = keep;
        while (t) {
            int b = (int)__ffsll(t) - 1;
            t &= t - 1;
            js[pos++] = (unsigned short)((lane << 6) + b);
        }
        __syncthreads();
        for (int k = lane; k < m; k += 64) {
            int j = js[k];
            ms[k] = scores[j];
            ds[k] = limit_period_f(boxes[j*7+6]);
        }
        __syncthreads();
        if (lane == 0) {
            if (m == 0) {
                for (int k = 0; k < 7; ++k) fused[i*7+k] = 0.0f;
                sfused[i] = 0.0f; validArr[i] = 0;
            } else {
                // s_sum and argmax (first occurrence of max; js ascending + strict >)
                float ssum = 0.0f, smax = -1e30f; int kref = 0;
                for (int k = 0; k < m; ++k) {
                    float sc = ms[k];
                    ssum += sc;
                    if (sc > smax) { smax = sc; kref = k; }
                }
                float refdir = ds[kref];
                float denom = fmaxf(ssum, 1e-12f);
                float sgt = 0.0f;
                float cd0=0,cd1=0,cd2=0,cd3=0,cd4=0,cd5=0;
                for (int k = 0; k < m; ++k) {
                    int j = js[k];
                    float sc = ms[k];
                    float d = fabsf(ds[k] - refdir);
                    if (d > PI_F) d = TWO_PI_F - d;
                    if (d > HALF_PI_F) sgt += sc;
                    float wgt = sc / denom;
                    cd0 += wgt * boxes[j*7+0];
                    cd1 += wgt * boxes[j*7+1];
                    cd2 += wgt * boxes[j*7+2];
                    cd3 += wgt * boxes[j*7+3];
                    cd4 += wgt * boxes[j*7+4];
                    cd5 += wgt * boxes[j*7+5];
                }
                float sle = ssum - sgt;
                bool flipGt = (sgt <= sle);
                float ssin = 0.0f, scos = 0.0f;
                for (int k = 0; k < m; ++k) {
                    float sc = ms[k];
                    float dj = ds[k];
                    float d = fabsf(dj - refdir);
                    if (d > PI_F) d = TWO_PI_F - d;
                    bool gt = d > HALF_PI_F;
                    bool flip = flipGt ? gt : !gt;
                    float adj_d = limit_period_f(dj + (flip ? PI_F : 0.0f));
                    float wgt = sc / denom;
                    ssin += sinf(adj_d) * wgt;
                    scos += cosf(adj_d) * wgt;
                }
                float theta = atan2f(ssin, scos);
                // s_fused: sort member scores descending, sum s_k^(k+1)
                for (int k = 1; k < m; ++k) {
                    float key = ms[k]; int p = k - 1;
                    while (p >= 0 && ms[p] < key) { ms[p+1] = ms[p]; --p; }
                    ms[p+1] = key;
                }
                float sf = 0.0f;
                for (int k = 0; k < m; ++k) sf += powf(ms[k], (float)(k+1));
                sf = fminf(sf, 1.0f);
                // corners range check
                float c_ = cosf(theta), s_ = sinf(theta);
                float wdim = cd4, ldim = cd5;
                const float xs[4]  = {0.5f, 0.5f, -0.5f, -0.5f};
                const float ys_[4] = {-0.5f, 0.5f, 0.5f, -0.5f};
                bool inr = true;
                for (int c = 0; c < 4; ++c) {
                    float cx = ldim * xs[c], cy = wdim * ys_[c];
                    float rx = cx*c_ - cy*s_ + cd0;
                    float ry = cx*s_ + cy*c_ + cd1;
                    inr = inr && (rx > -140.8f) && (rx < 140.8f) && (ry > -40.0f) && (ry < 40.0f);
                }
                fused[i*7+0]=cd0; fused[i*7+1]=cd1; fused[i*7+2]=cd2;
                fused[i*7+3]=cd3; fused[i*7+4]=cd4; fused[i*7+5]=cd5;
                fused[i*7+6]=theta;
                sfused[i] = sf;
                validArr[i] = inr ? 1 : 0;
            }
        }
        __syncthreads();
    }
}

// ---------------- Kernel 5: cumsum + gated output writes ----------------
__global__ void finalize_kernel(const float* __restrict__ fused,
                                const float* __restrict__ sfused,
                                const int* __restrict__ validArr,
                                const int* __restrict__ indices,
                                float* __restrict__ out, int n) {
    __shared__ int newidS[4096];
    __shared__ unsigned char validS[4096];
    __shared__ int scanBuf[1024];
    int tid = threadIdx.x;  // 1024
    int per = (n + 1023) >> 10;  // 4
    int base = tid * per;
    int v[8];
    int sum = 0;
    for (int k = 0; k < per && k < 8; ++k) {
        int j = base + k;
        int vv = (j < n) ? validArr[j] : 0;
        v[k] = vv; sum += vv;
    }
    scanBuf[tid] = sum;
    __syncthreads();
    for (int o = 1; o < 1024; o <<= 1) {
        int val = scanBuf[tid];
        int add = (tid >= o) ? scanBuf[tid - o] : 0;
        __syncthreads();
        scanBuf[tid] = val + add;
        __syncthreads();
    }
    int run = scanBuf[tid] - sum;
    for (int k = 0; k < per && k < 8; ++k) {
        int j = base + k;
        if (j < n) { run += v[k]; newidS[j] = run; validS[j] = (unsigned char)v[k]; }
    }
    __syncthreads();
    float* boxesO  = out;
    float* scoresO = out + (size_t)7*n;
    float* validO  = out + (size_t)8*n;
    float* idxO    = out + (size_t)9*n;
    for (int j = tid; j < n; j += 1024) {
        int vv = validS[j];
        #pragma unroll
        for (int k = 0; k < 7; ++k)
            boxesO[j*7+k] = vv ? fused[j*7+k] : 0.0f;
        scoresO[j] = vv ? sfused[j] : 0.0f;
        validO[j]  = vv ? 1.0f : 0.0f;
        int ind = indices[j];
        int safe = ind - 1; if (safe < 0) safe = 0;
        bool nv = (ind > 0) && (validS[safe] != 0);
        idxO[j] = nv ? (float)newidS[safe] : 0.0f;
    }
}

extern "C" void kernel_launch(void* const* d_in, const int* in_sizes, int n_in,
                              void* d_out, int out_size, void* d_ws, size_t ws_size,
                              hipStream_t stream) {
    const float* boxes  = (const float*)d_in[0];
    const float* scores = (const float*)d_in[1];
    int n = in_sizes[0] / 7;           // 4096
    int words = (n + 63) >> 6;         // 64

    char* ws = (char*)d_ws;
    size_t off = 0;
    u64* adjC = (u64*)(ws + off);
    off += (size_t)n * words * sizeof(u64);
    unsigned char* occByte = (unsigned char*)(ws + off); off += 64 * 64;
    u64* S = (u64*)(ws + off); off += 64 * sizeof(u64);
    int* seedList = (int*)(ws + off); off += (size_t)n * sizeof(int);
    int* indices  = (int*)(ws + off); off += (size_t)n * sizeof(int);
    float* fused  = (float*)(ws + off); off += (size_t)n * 7 * sizeof(float);
    float* sfused = (float*)(ws + off); off += (size_t)n * sizeof(float);
    int* validArr = (int*)(ws + off); off += (size_t)n * sizeof(int);
    int* nclust   = (int*)(ws + off); off += sizeof(int);

    dim3 adjGrid(words, (n + 255) / 256);
    adj_kernel<<<adjGrid, 256, 0, stream>>>(boxes, adjC, occByte, n, words);
    miscomp_kernel<<<words, 64, 0, stream>>>(adjC, occByte, S, n, words);
    indices_kernel<<<(n + 255) / 256, 256, 0, stream>>>(adjC, occByte, S, indices,
                                                        seedList, nclust, n, words);
    fusion_kernel<<<512, 64, 0, stream>>>(boxes, scores, indices, seedList, nclust,
                                          adjC, fused, sfused, validArr, n, words);
    finalize_kernel<<<1, 1024, 0, stream>>>(fused, sfused, validArr, indices,
                                            (float*)d_out, n);
}